// Round 2
// baseline (2075.060 us; speedup 1.0000x reference)
//
#include <hip/hip_runtime.h>
#include <math.h>

// B=32, R=16384, C=16, IC=16, OC=16, 3 routing iterations.
// x: (B,C,IC) fp32 [8192]; W: (R,C,OC,IC) fp32 [67108864 = 256 MB]; out: (B,C,OC) fp32.

#define RT 16384

#define DOT16(w0,w1,w2,w3,y0,y1,y2,y3) \
  (w0.x*y0.x + w0.y*y0.y + w0.z*y0.z + w0.w*y0.w + \
   w1.x*y1.x + w1.y*y1.y + w1.z*y1.z + w1.w*y1.w + \
   w2.x*y2.x + w2.y*y2.y + w2.z*y2.z + w2.w*y2.w + \
   w3.x*y3.x + w3.y*y3.y + w3.z*y3.z + w3.w*y3.w)

// ---------------------------------------------------------------------------
// K1: wsum[c,o,i] = sum_r W[r,c,o,i].  W = 16,777,216 float4s.
// 262144 threads x 64 iters, stride 262144 (multiple of 1024 so each thread
// stays on one (c,o,i4) class across all its r's). 4 atomicAdds per thread.
// ---------------------------------------------------------------------------
__global__ __launch_bounds__(256) void k_wsum(const float4* __restrict__ W4,
                                              float* __restrict__ wsum) {
    int gid = blockIdx.x * 256 + threadIdx.x;      // [0, 262144)
    float4 acc = {0.f, 0.f, 0.f, 0.f};
    int idx = gid;
    #pragma unroll
    for (int it = 0; it < 64; ++it) {              // 16777216 / 262144 = 64
        float4 w = W4[idx];
        acc.x += w.x; acc.y += w.y; acc.z += w.z; acc.w += w.w;
        idx += 262144;
    }
    int cls = gid & 1023;                          // (c,o,i4) within an r-block
    atomicAdd(&wsum[cls * 4 + 0], acc.x);
    atomicAdd(&wsum[cls * 4 + 1], acc.y);
    atomicAdd(&wsum[cls * 4 + 2], acc.z);
    atomicAdd(&wsum[cls * 4 + 3], acc.w);
}

// ---------------------------------------------------------------------------
// K2: s1 = (1/R) * wsum . x ;  v1 = squash(s1)  -> v1[b*256 + c*16 + o]
// ---------------------------------------------------------------------------
__global__ __launch_bounds__(256) void k_v1(const float* __restrict__ wsum,
                                            const float* __restrict__ x,
                                            float* __restrict__ v1) {
    int t = blockIdx.x * 256 + threadIdx.x;        // 0..8191
    int o = t & 15, c = (t >> 4) & 15, b = t >> 8;
    const float* xb = x + (b * 16 + c) * 16;
    const float* wr = wsum + (c * 16 + o) * 16;
    float s = 0.f;
    #pragma unroll
    for (int i = 0; i < 16; ++i) s += wr[i] * xb[i];
    s *= (1.0f / 16384.0f);
    float ns = s * s;
    #pragma unroll
    for (int d = 1; d < 16; d <<= 1) ns += __shfl_xor(ns, d);
    v1[t] = s * (sqrtf(ns) / (1.0f + ns));
}

// ---------------------------------------------------------------------------
// K4: s = E/Z, v = squash(s) -> dst (v2 buffer or final out)
// ---------------------------------------------------------------------------
__global__ __launch_bounds__(256) void k_vout(const float* __restrict__ E,
                                              const float* __restrict__ Z,
                                              float* __restrict__ dst) {
    int t = blockIdx.x * 256 + threadIdx.x;        // 0..8191
    float s = E[t] / Z[t >> 4];                    // t>>4 = b*16+c
    float ns = s * s;
    #pragma unroll
    for (int d = 1; d < 16; d <<= 1) ns += __shfl_xor(ns, d);
    dst[t] = s * (sqrtf(ns) / (1.0f + ns));
}

// ---------------------------------------------------------------------------
// K3: fused routing pass.  For each (b,c,r):
//   u[o]  = sum_i W[r,c,o,i] * x[b,c,i]       (W tile staged in LDS, XOR swizzle)
//   L     = sum_o u[o] * v[b,c,o]  (+ Lprev if PASS3)
//   e     = exp(L)   (no max subtraction -- |L| <= ~30, safe in fp32)
//   E[b,c,o] += e * u[o] ;  Z[b,c] += e
// Block 512 = 8 waves; wave wv owns b in {4wv..4wv+3}; lane = r within the
// 64-row chunk; 4 chunks per block. Grid (64, 16) -> covers r, c.
// Epilogue: 6-stage butterfly over 68 per-lane values, 1 atomicAdd per lane.
// ---------------------------------------------------------------------------
template <int PASS3>
__global__ __launch_bounds__(512, 2) void k_iter(const float* __restrict__ W,
                                                 const float* __restrict__ x,
                                                 const float* __restrict__ v,
                                                 float* __restrict__ L,
                                                 float* __restrict__ E,
                                                 float* __restrict__ Z) {
    __shared__ float4 Wl[64 * 64];                 // 64 KB: 64 rows x 64 float4
    int c = blockIdx.y;
    int r0 = blockIdx.x * 256;
    int tid = threadIdx.x, wv = tid >> 6, lane = tid & 63;

    // x rows for this wave's 4 b's (wave-uniform values, kept per-lane in VGPRs)
    float4 xr[4][4];
    #pragma unroll
    for (int bl = 0; bl < 4; ++bl) {
        const float4* xb = (const float4*)(x + ((wv * 4 + bl) * 16 + c) * 16);
        xr[bl][0] = xb[0]; xr[bl][1] = xb[1]; xr[bl][2] = xb[2]; xr[bl][3] = xb[3];
    }
    float accE[4][16];
    float accZ[4] = {0.f, 0.f, 0.f, 0.f};
    #pragma unroll
    for (int bl = 0; bl < 4; ++bl)
        #pragma unroll
        for (int o = 0; o < 16; ++o) accE[bl][o] = 0.f;

    for (int chunk = 0; chunk < 4; ++chunk) {
        int rbase = r0 + chunk * 64;
        __syncthreads();
        #pragma unroll
        for (int k = 0; k < 8; ++k) {              // stage 64 rows x 1 KB
            int t = tid + k * 512;
            int rl = t >> 6, j = t & 63;
            Wl[rl * 64 + (j ^ rl)] =
                *(const float4*)(W + ((size_t)(rbase + rl) * 16 + c) * 256 + j * 4);
        }
        __syncthreads();

        float u[4][16];
        #pragma unroll
        for (int o = 0; o < 16; ++o) {
            float4 w0 = Wl[lane * 64 + ((o * 4 + 0) ^ lane)];
            float4 w1 = Wl[lane * 64 + ((o * 4 + 1) ^ lane)];
            float4 w2 = Wl[lane * 64 + ((o * 4 + 2) ^ lane)];
            float4 w3 = Wl[lane * 64 + ((o * 4 + 3) ^ lane)];
            #pragma unroll
            for (int bl = 0; bl < 4; ++bl)
                u[bl][o] = DOT16(w0, w1, w2, w3,
                                 xr[bl][0], xr[bl][1], xr[bl][2], xr[bl][3]);
        }

        int r = rbase + lane;
        #pragma unroll
        for (int bl = 0; bl < 4; ++bl) {
            int bc = (wv * 4 + bl) * 16 + c;
            const float* vb = v + bc * 16;
            float Lv = 0.f;
            #pragma unroll
            for (int o = 0; o < 16; ++o) Lv += u[bl][o] * vb[o];
            size_t li = (size_t)bc * RT + r;
            if (PASS3) Lv += L[li];
            else       L[li] = Lv;
            float e = __expf(Lv);
            accZ[bl] += e;
            #pragma unroll
            for (int o = 0; o < 16; ++o) accE[bl][o] += e * u[bl][o];
        }
    }

    // Butterfly-reduce the 64 accE values + 4 accZ over the 64 lanes.
    float va = 0.f;
    #pragma unroll
    for (int bl = 0; bl < 4; ++bl) {
        #pragma unroll
        for (int o = 0; o < 16; ++o) {
            float t = accE[bl][o];
            #pragma unroll
            for (int d = 1; d < 64; d <<= 1) t += __shfl_xor(t, d);
            if (lane == bl * 16 + o) va = t;
        }
    }
    float vz = 0.f;
    #pragma unroll
    for (int bl = 0; bl < 4; ++bl) {
        float t = accZ[bl];
        #pragma unroll
        for (int d = 1; d < 64; d <<= 1) t += __shfl_xor(t, d);
        if (lane == bl) vz = t;
    }
    int b = wv * 4 + (lane >> 4);
    atomicAdd(&E[b * 256 + c * 16 + (lane & 15)], va);
    if (lane < 4) atomicAdd(&Z[(wv * 4 + lane) * 16 + c], vz);
}

// ---------------------------------------------------------------------------
// launch
// ---------------------------------------------------------------------------
extern "C" void kernel_launch(void* const* d_in, const int* in_sizes, int n_in,
                              void* d_out, int out_size, void* d_ws, size_t ws_size,
                              hipStream_t stream) {
    const float* x = (const float*)d_in[0];        // 8192 floats
    const float* W = (const float*)d_in[1];        // 67108864 floats (256 MB)
    float* out = (float*)d_out;                    // 8192 floats
    float* ws = (float*)d_ws;

    float* wsum = ws + 0;          // 4096
    float* E2   = ws + 4096;       // 8192
    float* Z2   = ws + 12288;      // 512
    float* E3   = ws + 12800;      // 8192
    float* Z3   = ws + 20992;      // 512   (accumulated region ends at 21504)
    float* v1   = ws + 21504;      // 8192
    float* v2   = ws + 29696;      // 8192
    float* L    = ws + 37888;      // 8388608 (33.5 MB)

    hipMemsetAsync(ws, 0, 21504 * sizeof(float), stream);

    // iter 1: uniform softmax -> v1 from Wsum (W pass 1)
    k_wsum<<<1024, 256, 0, stream>>>((const float4*)W, wsum);
    k_v1<<<32, 256, 0, stream>>>(wsum, x, v1);

    // iter 2 fused: L2 = <u, v1>, E2/Z2 accumulated in-pass (W pass 2)
    k_iter<0><<<dim3(64, 16), 512, 0, stream>>>(W, x, v1, L, E2, Z2);
    k_vout<<<32, 256, 0, stream>>>(E2, Z2, v2);    // v2 = squash(E2/Z2)

    // iter 3 fused: L3 = L2 + <u, v2>, E3/Z3 accumulated (W pass 3)
    k_iter<1><<<dim3(64, 16), 512, 0, stream>>>(W, x, v2, L, E3, Z3);
    k_vout<<<32, 256, 0, stream>>>(E3, Z3, out);   // out = squash(E3/Z3)
}